// Round 1
// baseline (346.743 us; speedup 1.0000x reference)
//
#include <hip/hip_runtime.h>

#define LW 16
#define CLASSNUM 1000
#define DIM (CLASSNUM * LW)   // 16000
#define NROWS 4096
#define BLK 256

// One block per row: block-reduce sum(x^2), then thread 0 adds the
// gathered/weighted terms and writes a per-row partial to ws.
__global__ __launch_bounds__(BLK) void rvs_row_kernel(
    const float* __restrict__ inputs,
    const float* __restrict__ labels,
    float* __restrict__ ws) {
    const int row = blockIdx.x;
    const int tid = threadIdx.x;
    const float* rowp = inputs + (size_t)row * DIM;
    const float4* rowp4 = (const float4*)rowp;   // DIM % 4 == 0, 16B-aligned

    float s = 0.0f;
    // DIM/4 = 4000 float4 per row; 16 strided iterations of 256 threads.
    #pragma unroll
    for (int k = 0; k < 16; ++k) {
        int idx = k * BLK + tid;
        if (idx < DIM / 4) {
            float4 v = rowp4[idx];
            s += v.x * v.x + v.y * v.y + v.z * v.z + v.w * v.w;
        }
    }

    // wave64 shuffle reduce
    #pragma unroll
    for (int off = 32; off > 0; off >>= 1)
        s += __shfl_down(s, off, 64);

    __shared__ float wsum_lds[BLK / 64];
    const int lane = tid & 63;
    const int wv = tid >> 6;
    if (lane == 0) wsum_lds[wv] = s;
    __syncthreads();

    if (tid == 0) {
        float sq = 0.0f;
        #pragma unroll
        for (int i = 0; i < BLK / 64; ++i) sq += wsum_lds[i];

        const float* lab = labels + row * (LW + 1);
        const int c = (int)lab[LW];
        const float* g = rowp + c * LW;   // 16 contiguous floats

        float wsum = 0.0f, lin = 0.0f;
        #pragma unroll
        for (int j = 0; j < LW; ++j) {
            float wj = lab[j];
            wsum += wj;
            lin += wj * (1.0f - 2.0f * g[j]);
        }
        ws[row] = sq * wsum + lin;
    }
}

// Single-block reduction of the 4096 per-row partials.
__global__ __launch_bounds__(BLK) void rvs_reduce_kernel(
    const float* __restrict__ ws, float* __restrict__ out) {
    const int tid = threadIdx.x;
    float s = 0.0f;
    for (int i = tid; i < NROWS; i += BLK) s += ws[i];

    #pragma unroll
    for (int off = 32; off > 0; off >>= 1)
        s += __shfl_down(s, off, 64);

    __shared__ float wsum_lds[BLK / 64];
    const int lane = tid & 63;
    const int wv = tid >> 6;
    if (lane == 0) wsum_lds[wv] = s;
    __syncthreads();

    if (tid == 0) {
        float t = 0.0f;
        #pragma unroll
        for (int i = 0; i < BLK / 64; ++i) t += wsum_lds[i];
        out[0] = t / (float)NROWS;
    }
}

extern "C" void kernel_launch(void* const* d_in, const int* in_sizes, int n_in,
                              void* d_out, int out_size, void* d_ws, size_t ws_size,
                              hipStream_t stream) {
    const float* inputs = (const float*)d_in[0];   // (4096, 16000) f32
    const float* labels = (const float*)d_in[1];   // (4096, 17)    f32
    float* out = (float*)d_out;                    // (1,) f32
    float* ws = (float*)d_ws;                      // >= 4096 floats

    rvs_row_kernel<<<NROWS, BLK, 0, stream>>>(inputs, labels, ws);
    rvs_reduce_kernel<<<1, BLK, 0, stream>>>(ws, out);
}